// Round 1
// baseline (97.852 us; speedup 1.0000x reference)
//
#include <hip/hip_runtime.h>

// UnarySqrt bitstream scan: L=64 steps over N=2^20 independent columns.
// Each thread owns 4 consecutive columns (float4), keeps the tiny integer
// state in registers, streams one row in / one row out per step.
// Memory-bound: 512 MiB total traffic, floor ~85 us at 6.3 TB/s.

#define STEPS 64

__global__ __launch_bounds__(256)
void unary_sqrt_kernel(const float* __restrict__ bits,
                       float* __restrict__ out, int N) {
    const int t  = blockIdx.x * blockDim.x + threadIdx.x;
    const int n4 = t * 4;
    if (n4 >= N) return;

    const float4* __restrict__ in4  = reinterpret_cast<const float4*>(bits + n4);
    float4* __restrict__       out4 = reinterpret_cast<float4*>(out + n4);
    const int stride4 = N >> 2;   // row stride in float4 units

    int cnt[4] = {0, 0, 0, 0};
    int sr [4] = {1, 1, 1, 1};   // historic quotient init = 1
    int acc[4] = {0, 0, 0, 0};

    #pragma unroll 4
    for (int l = 0; l < STEPS; ++l) {
        const float4 v = in4[(size_t)l * stride4];
        float xf[4] = {v.x, v.y, v.z, v.w};
        float o[4];
        #pragma unroll
        for (int j = 0; j < 4; ++j) {
            const int x       = xf[j] > 0.5f;          // input bit
            const int emit_en = (x ^ 1) & (acc[j] > 0);
            const int ot      = x | emit_en;           // output bit
            const int cnm     = (cnt[j] != 0);         // cnt not min
            const int cnx     = (cnt[j] != 3);         // cnt not max
            // out==1: release from sync buffer; out==0: try to buffer
            const int q = ot ? cnm : sr[j];
            cnt[j] += ot ? -cnm : cnx;
            sr[j]   = ot ? q : sr[j];                  // sr takes q only when divisor==1
            acc[j]  = min(max(acc[j] + q - emit_en, 0), 7);
            o[j] = (float)ot;
        }
        out4[(size_t)l * stride4] = make_float4(o[0], o[1], o[2], o[3]);
    }
}

extern "C" void kernel_launch(void* const* d_in, const int* in_sizes, int n_in,
                              void* d_out, int out_size, void* d_ws, size_t ws_size,
                              hipStream_t stream) {
    const float* bits = (const float*)d_in[0];
    float* out = (float*)d_out;
    const int total = in_sizes[0];        // L * N
    const int N = total / STEPS;

    const int threads = 256;
    const int blocks  = (N / 4 + threads - 1) / threads;
    unary_sqrt_kernel<<<blocks, threads, 0, stream>>>(bits, out, N);
}